// Round 1
// baseline (135.318 us; speedup 1.0000x reference)
//
#include <hip/hip_runtime.h>
#include <hip/hip_bf16.h>

typedef __attribute__((ext_vector_type(8))) short bf16x8;
typedef __attribute__((ext_vector_type(4))) float f32x4;

#define B_N   16384
#define INP_N 4096
#define M_N   100
#define K_N   32
#define HID_N 32
#define OUT_W 10

// ---------------- workspace layout (bytes) ----------------
#define WS_TW1 0u         // bf16[100][32][32]   tW1[m][h][k]      204800
#define WS_TW2 204800u    // bf16[100][16][32]   tW2[m][o(pad)][h] 102400
#define WS_TB1 307200u    // f32 [100][32]       tb1               12800
#define WS_TB2 320000u    // f32 [100][16]       tb2               6400
#define WS_COL 326400u    // u16 [100][32]       idx cols packed   6400
// total 332800 B

// ---------------- kernel-2 LDS layout ----------------
#define ROWB   8208                 // bf16 row: 8192 B data + 16 B pad (bank rotate, 16B aligned)
#define BUFB   (8 * ROWB)           // 65664 per tile buffer (8 rows)
#define THOFF  (2 * BUFB)           // 131328: per-wave th bounce / out-red (aliased)
#define THWB   1152                 // 8 rows x 36 f32 (row stride 36 -> conflict-free, 16B aligned)
#define TB2OFF (THOFF + 8 * THWB)   // 140544
#define LDS_SZ (TB2OFF + 64)        // 140608  (<= 160 KiB)

__device__ __forceinline__ unsigned int pkbf(float a, float b) {
    __hip_bfloat162 h2 = __float22bfloat162_rn(make_float2(a, b));
    unsigned int r;
    __builtin_memcpy(&r, &h2, 4);
    return r;
}

// =====================================================================
// Kernel 1: hypernetwork.  One block per m.  f32 compute, emits bf16
// weights in MFMA fragment-friendly layouts + packed column offsets.
// =====================================================================
__global__ __launch_bounds__(256) void hyper_kernel(
    const int* __restrict__ idx,
    const float* __restrict__ Wi, const float* __restrict__ bi,
    const float* __restrict__ W1, const float* __restrict__ b1,
    const float* __restrict__ W2, const float* __restrict__ b2,
    const float* __restrict__ Wo, const float* __restrict__ bo,
    char* __restrict__ ws)
{
    __shared__ int   s_idx[K_N];
    __shared__ float s_h0[64];
    __shared__ float s_h1[256];
    __shared__ float s_h2[128];
    const int m = blockIdx.x;
    const int t = threadIdx.x;

    __hip_bfloat16* tW1bf = (__hip_bfloat16*)(ws + WS_TW1);
    __hip_bfloat16* tW2bf = (__hip_bfloat16*)(ws + WS_TW2);
    float* tb1f = (float*)(ws + WS_TB1);
    float* tb2f = (float*)(ws + WS_TB2);
    unsigned short* colb = (unsigned short*)(ws + WS_COL);

    if (t < K_N) {
        int c = idx[m * K_N + t];
        s_idx[t] = c;
        colb[m * K_N + t] = (unsigned short)c;
    }
    __syncthreads();

    // h0 = relu(mask @ Wi.T + bi): sum over UNIQUE idx columns (idx sorted)
    if (t < 64) {
        float s = bi[t];
        const float* wr = Wi + t * INP_N;
        int prev = -1;
        for (int k = 0; k < K_N; ++k) {
            int c = s_idx[k];
            if (c != prev) s += wr[c];
            prev = c;
        }
        s_h0[t] = fmaxf(s, 0.f);
    }
    __syncthreads();

    { // h1 = relu(W1 h0 + b1), 256 outputs
        float s = b1[t];
        const float* wr = W1 + t * 64;
        #pragma unroll
        for (int i = 0; i < 64; ++i) s += wr[i] * s_h0[i];
        s_h1[t] = fmaxf(s, 0.f);
    }
    __syncthreads();

    if (t < 128) { // h2 = relu(W2 h1 + b2)
        float s = b2[t];
        const float* wr = W2 + t * 256;
        for (int i = 0; i < 256; ++i) s += wr[i] * s_h1[i];
        s_h2[t] = fmaxf(s, 0.f);
    }
    __syncthreads();

    // w = Wo h2 + bo (1386 outputs), routed to the four tensors
    for (int o = t; o < 1386; o += 256) {
        float s = bo[o];
        const float* wr = Wo + o * 128;
        for (int i = 0; i < 128; ++i) s += wr[i] * s_h2[i];
        if (o < 1024) {                     // tW1[m][h][k], h=o>>5, k=o&31
            tW1bf[m * 1024 + o] = __float2bfloat16(s);
        } else if (o < 1056) {
            tb1f[m * 32 + (o - 1024)] = s;
        } else if (o < 1376) {              // tW2[m][o'][h], o'=i>>5, h=i&31
            int i2 = o - 1056;
            tW2bf[m * 512 + i2] = __float2bfloat16(s);
        } else {
            tb2f[m * 16 + (o - 1376)] = s;
        }
    }
    // zero the padded tW2 rows o'=10..15 so MFMA pad lanes contribute 0
    if (t < 192) tW2bf[m * 512 + 320 + t] = __float2bfloat16(0.f);
}

// =====================================================================
// Kernel 2: main loop.  256 blocks (1/CU) x 512 thr (8 waves).
// Block: 8 tiles of 8 data rows; rows staged f32->bf16 in LDS,
// double-buffered; waves split the 100 m's; 3x mfma_16x16x32_bf16 per
// (tile, m); outT accumulated in C-frag across m; cross-wave reduce.
// =====================================================================
__global__ __launch_bounds__(512, 2) void main_kernel(
    const float* __restrict__ data,
    const char* __restrict__ ws,
    float* __restrict__ out)
{
    extern __shared__ char smem[];
    const int tid  = threadIdx.x;
    const int lane = tid & 63;
    const int wave = tid >> 6;       // 0..7 ; wave w stages data row w of each tile
    const int kg   = lane >> 4;      // 0..3  (MFMA k-group)
    const int ln15 = lane & 15;

    float* tb2s = (float*)(smem + TB2OFF);
    if (tid < OUT_W) {               // b-independent bias term: sum_m tb2[m][o]
        const float* tb2f = (const float*)(ws + WS_TB2);
        float s = 0.f;
        for (int m = 0; m < M_N; ++m) s += tb2f[m * 16 + tid];
        tb2s[tid] = s;
    }

    const int tile0 = blockIdx.x * 8;
    const int mlo = (wave * M_N) >> 3;
    const int mhi = ((wave + 1) * M_N) >> 3;

    float4 v[16];                    // staging registers (one 16KB row / wave)

    // ---- prologue: stage tile0 into buf0 ----
    {
        const float* rp = data + (size_t)(tile0 * 8 + wave) * INP_N;
        #pragma unroll
        for (int j = 0; j < 8; ++j) {
            v[2 * j]     = *(const float4*)(rp + j * 512 + lane * 8);
            v[2 * j + 1] = *(const float4*)(rp + j * 512 + lane * 8 + 4);
        }
        char* bp = smem + wave * ROWB;
        #pragma unroll
        for (int j = 0; j < 8; ++j) {
            uint4 pk;
            pk.x = pkbf(v[2 * j].x,     v[2 * j].y);
            pk.y = pkbf(v[2 * j].z,     v[2 * j].w);
            pk.z = pkbf(v[2 * j + 1].x, v[2 * j + 1].y);
            pk.w = pkbf(v[2 * j + 1].z, v[2 * j + 1].w);
            *(uint4*)(bp + j * 1024 + lane * 16) = pk;
        }
    }
    __syncthreads();

    for (int ti = 0; ti < 8; ++ti) {
        const int cur = ti & 1;
        // issue next-tile global loads EARLY (hide HBM under compute)
        if (ti < 7) {
            const float* rp = data + (size_t)((tile0 + ti + 1) * 8 + wave) * INP_N;
            #pragma unroll
            for (int j = 0; j < 8; ++j) {
                v[2 * j]     = *(const float4*)(rp + j * 512 + lane * 8);
                v[2 * j + 1] = *(const float4*)(rp + j * 512 + lane * 8 + 4);
            }
        }

        // ---- compute current tile ----
        const char* gbase = smem + cur * BUFB + (lane & 7) * ROWB;
        float* thp = (float*)(smem + THOFF + wave * THWB);
        f32x4 acc = {0.f, 0.f, 0.f, 0.f};

        for (int m = mlo; m < mhi; ++m) {
            // A-frag: md[b=ln15][k=kg*8+j] gathered from staged bf16 row
            const uint4 cw = *(const uint4*)(ws + WS_COL + m * 64 + kg * 16);
            unsigned short u0 = *(const unsigned short*)(gbase + 2 * (cw.x & 0xFFFFu));
            unsigned short u1 = *(const unsigned short*)(gbase + 2 * (cw.x >> 16));
            unsigned short u2 = *(const unsigned short*)(gbase + 2 * (cw.y & 0xFFFFu));
            unsigned short u3 = *(const unsigned short*)(gbase + 2 * (cw.y >> 16));
            unsigned short u4 = *(const unsigned short*)(gbase + 2 * (cw.z & 0xFFFFu));
            unsigned short u5 = *(const unsigned short*)(gbase + 2 * (cw.z >> 16));
            unsigned short u6 = *(const unsigned short*)(gbase + 2 * (cw.w & 0xFFFFu));
            unsigned short u7 = *(const unsigned short*)(gbase + 2 * (cw.w >> 16));
            union { unsigned int ui[4]; bf16x8 v8; } af;
            af.ui[0] = (unsigned int)u0 | ((unsigned int)u1 << 16);
            af.ui[1] = (unsigned int)u2 | ((unsigned int)u3 << 16);
            af.ui[2] = (unsigned int)u4 | ((unsigned int)u5 << 16);
            af.ui[3] = (unsigned int)u6 | ((unsigned int)u7 << 16);

            // B-frags: tW1[m][h][k] rows (h=ln15 and h=ln15+16), 8 consecutive k
            const bf16x8 w1a = *(const bf16x8*)(ws + WS_TW1 + m * 2048 + ln15 * 64 + kg * 16);
            const bf16x8 w1b = *(const bf16x8*)(ws + WS_TW1 + m * 2048 + 1024 + ln15 * 64 + kg * 16);
            const bf16x8 w2f = *(const bf16x8*)(ws + WS_TW2 + m * 1024 + ln15 * 64 + kg * 16);
            const float tb10 = *(const float*)(ws + WS_TB1 + m * 128 + ln15 * 4);
            const float tb11 = *(const float*)(ws + WS_TB1 + m * 128 + 64 + ln15 * 4);

            f32x4 c0 = {tb10, tb10, tb10, tb10};   // bias as C-in (free add)
            f32x4 c1 = {tb11, tb11, tb11, tb11};
            c0 = __builtin_amdgcn_mfma_f32_16x16x32_bf16(af.v8, w1a, c0, 0, 0, 0);
            c1 = __builtin_amdgcn_mfma_f32_16x16x32_bf16(af.v8, w1b, c1, 0, 0, 0);

            // relu + bounce th (rows b=0..7 only; C row=(lane>>4)*4+r, col h=ln15)
            if (lane < 32) {
                const int b0 = kg * 4;
                #pragma unroll
                for (int r = 0; r < 4; ++r) {
                    thp[(b0 + r) * 36 + ln15]      = fmaxf(c0[r], 0.f);
                    thp[(b0 + r) * 36 + ln15 + 16] = fmaxf(c1[r], 0.f);
                }
            }
            // stage2 B-frag: th[b=ln15(&7)][h=kg*8+j] -> bf16
            const float4 t0 = *(const float4*)(thp + (lane & 7) * 36 + kg * 8);
            const float4 t1 = *(const float4*)(thp + (lane & 7) * 36 + kg * 8 + 4);
            union { unsigned int ui[4]; bf16x8 v8; } bfr;
            bfr.ui[0] = pkbf(t0.x, t0.y);
            bfr.ui[1] = pkbf(t0.z, t0.w);
            bfr.ui[2] = pkbf(t1.x, t1.y);
            bfr.ui[3] = pkbf(t1.z, t1.w);
            // outT[o][b] += tW2[o][h] x th[h][b]
            acc = __builtin_amdgcn_mfma_f32_16x16x32_bf16(w2f, bfr.v8, acc, 0, 0, 0);
        }

        // per-wave partial outT -> red (aliases own th region; safe)
        {
            float* red = (float*)(smem + THOFF + wave * THWB);
            #pragma unroll
            for (int r = 0; r < 4; ++r)
                red[(kg * 4 + r) * 16 + ln15] = acc[r];
        }
        // cvt + write next tile into the other buffer
        if (ti < 7) {
            char* bp = smem + (1 - cur) * BUFB + wave * ROWB;
            #pragma unroll
            for (int j = 0; j < 8; ++j) {
                uint4 pk;
                pk.x = pkbf(v[2 * j].x,     v[2 * j].y);
                pk.y = pkbf(v[2 * j].z,     v[2 * j].w);
                pk.z = pkbf(v[2 * j + 1].x, v[2 * j + 1].y);
                pk.w = pkbf(v[2 * j + 1].z, v[2 * j + 1].w);
                *(uint4*)(bp + j * 1024 + lane * 16) = pk;
            }
        }
        __syncthreads();

        // reduce 8 waves + tb2 + mean, write out
        if (tid < 80) {
            const int o = tid >> 3, b = tid & 7;
            float s = tb2s[o];
            #pragma unroll
            for (int w = 0; w < 8; ++w)
                s += ((const float*)(smem + THOFF + w * THWB))[o * 16 + b];
            out[(size_t)((tile0 + ti) * 8 + b) * OUT_W + o] = s * 0.01f;
        }
        __syncthreads();   // protect red/th alias + buffers before next tile
    }
}

extern "C" void kernel_launch(void* const* d_in, const int* in_sizes, int n_in,
                              void* d_out, int out_size, void* d_ws, size_t ws_size,
                              hipStream_t stream) {
    const float* data = (const float*)d_in[0];
    const int*   idx  = (const int*)d_in[1];
    const float* Wi = (const float*)d_in[2];
    const float* bi = (const float*)d_in[3];
    const float* W1 = (const float*)d_in[4];
    const float* b1 = (const float*)d_in[5];
    const float* W2 = (const float*)d_in[6];
    const float* b2 = (const float*)d_in[7];
    const float* Wo = (const float*)d_in[8];
    const float* bo = (const float*)d_in[9];
    float* out = (float*)d_out;
    char* ws = (char*)d_ws;

    (void)hipFuncSetAttribute((const void*)main_kernel,
                              hipFuncAttributeMaxDynamicSharedMemorySize, LDS_SZ);

    hipLaunchKernelGGL(hyper_kernel, dim3(M_N), dim3(256), 0, stream,
                       idx, Wi, bi, W1, b1, W2, b2, Wo, bo, ws);
    hipLaunchKernelGGL(main_kernel, dim3(256), dim3(512), LDS_SZ, stream,
                       data, ws, out);
}

// Round 2
// 113.709 us; speedup vs baseline: 1.1900x; 1.1900x over previous
//
#include <hip/hip_runtime.h>
#include <hip/hip_bf16.h>

typedef __attribute__((ext_vector_type(8))) short bf16x8;
typedef __attribute__((ext_vector_type(4))) float f32x4;

#define B_N   16384
#define INP_N 4096
#define M_N   100
#define K_N   32
#define HID_N 32
#define OUT_W 10

// ---------------- workspace layout (bytes) ----------------
#define WS_TW1 0u         // bf16[100][32][32]   tW1[m][h][k]      204800
#define WS_TW2 204800u    // bf16[100][16][32]   tW2[m][o(pad)][h] 102400
#define WS_TB1 307200u    // f32 [100][32]       tb1               12800
#define WS_TB2 320000u    // f32 [100][16]       tb2               6400
#define WS_COL 326400u    // u16 [100][32]       idx cols packed   6400
#define WS_H2  332800u    // f32 [100][128]      h2 activations    51200
// total 384000 B

// ---------------- kernel-2 LDS layout ----------------
#define ROWB   8208                 // bf16 row: 8192 B data + 16 B pad (bank rotate, 16B aligned)
#define BUFB   (8 * ROWB)           // 65664 per tile buffer (8 rows)
#define THOFF  (2 * BUFB)           // 131328: per-wave th bounce / out-red (aliased)
#define THWB   1152                 // 8 rows x 36 f32 (row stride 36 -> conflict-free, 16B aligned)
#define NWAVE  16
#define TB2OFF (THOFF + NWAVE * THWB)   // 149760
#define LDS_SZ (TB2OFF + 64)            // 149824  (<= 160 KiB)

__device__ __forceinline__ unsigned int pkbf(float a, float b) {
    __hip_bfloat162 h2 = __float22bfloat162_rn(make_float2(a, b));
    unsigned int r;
    __builtin_memcpy(&r, &h2, 4);
    return r;
}

// =====================================================================
// Kernel 1a: hypernet trunk (h0 -> h1 -> h2).  One block per m.
// =====================================================================
__global__ __launch_bounds__(256) void hyperA_kernel(
    const int* __restrict__ idx,
    const float* __restrict__ Wi, const float* __restrict__ bi,
    const float* __restrict__ W1, const float* __restrict__ b1,
    const float* __restrict__ W2, const float* __restrict__ b2,
    char* __restrict__ ws)
{
    __shared__ int   s_idx[K_N];
    __shared__ float s_h0[64];
    __shared__ float s_h1[256];
    const int m = blockIdx.x;
    const int t = threadIdx.x;

    unsigned short* colb = (unsigned short*)(ws + WS_COL);
    float* h2p = (float*)(ws + WS_H2);

    if (t < K_N) {
        int c = idx[m * K_N + t];
        s_idx[t] = c;
        colb[m * K_N + t] = (unsigned short)c;
    }
    __syncthreads();

    // h0 = relu(mask @ Wi.T + bi): sum over UNIQUE idx columns (idx sorted)
    if (t < 64) {
        float s = bi[t];
        const float* wr = Wi + t * INP_N;
        int prev = -1;
        for (int k = 0; k < K_N; ++k) {
            int c = s_idx[k];
            if (c != prev) s += wr[c];
            prev = c;
        }
        s_h0[t] = fmaxf(s, 0.f);
    }
    __syncthreads();

    { // h1 = relu(W1 h0 + b1), 256 outputs, float4-vectorized
        float s = b1[t];
        const float4* wr = (const float4*)(W1 + t * 64);
        const float4* h0v = (const float4*)s_h0;
        #pragma unroll
        for (int i = 0; i < 16; ++i) {
            float4 w4 = wr[i], a4 = h0v[i];
            s += w4.x * a4.x + w4.y * a4.y + w4.z * a4.z + w4.w * a4.w;
        }
        s_h1[t] = fmaxf(s, 0.f);
    }
    __syncthreads();

    if (t < 128) { // h2 = relu(W2 h1 + b2), float4-vectorized
        float s = b2[t];
        const float4* wr = (const float4*)(W2 + t * 256);
        const float4* h1v = (const float4*)s_h1;
        #pragma unroll
        for (int i = 0; i < 64; ++i) {
            float4 w4 = wr[i], a4 = h1v[i];
            s += w4.x * a4.x + w4.y * a4.y + w4.z * a4.z + w4.w * a4.w;
        }
        h2p[m * 128 + t] = fmaxf(s, 0.f);
    }
}

// =====================================================================
// Kernel 1b: hypernet head (w = Wo h2 + bo), routed to weight tensors.
// Grid (100, 6) x 256 threads: one output per thread (1536 >= 1386).
// =====================================================================
__global__ __launch_bounds__(256) void hyperB_kernel(
    const float* __restrict__ Wo, const float* __restrict__ bo,
    char* __restrict__ ws)
{
    __shared__ float h2s[128];
    const int m = blockIdx.x;
    const int seg = blockIdx.y;
    const int t = threadIdx.x;

    __hip_bfloat16* tW1bf = (__hip_bfloat16*)(ws + WS_TW1);
    __hip_bfloat16* tW2bf = (__hip_bfloat16*)(ws + WS_TW2);
    float* tb1f = (float*)(ws + WS_TB1);
    float* tb2f = (float*)(ws + WS_TB2);
    const float* h2p = (const float*)(ws + WS_H2);

    if (t < 128) h2s[t] = h2p[m * 128 + t];
    __syncthreads();

    const int o = seg * 256 + t;
    if (o < 1386) {
        float s = bo[o];
        const float4* wr = (const float4*)(Wo + o * 128);
        const float4* h2v = (const float4*)h2s;
        #pragma unroll
        for (int i = 0; i < 32; ++i) {
            float4 w4 = wr[i], a4 = h2v[i];
            s += w4.x * a4.x + w4.y * a4.y + w4.z * a4.z + w4.w * a4.w;
        }
        if (o < 1024) {                     // tW1[m][h][k], h=o>>5, k=o&31
            tW1bf[m * 1024 + o] = __float2bfloat16(s);
        } else if (o < 1056) {
            tb1f[m * 32 + (o - 1024)] = s;
        } else if (o < 1376) {              // tW2[m][o'][h], o'=i>>5, h=i&31
            tW2bf[m * 512 + (o - 1056)] = __float2bfloat16(s);
        } else {
            tb2f[m * 16 + (o - 1376)] = s;
        }
    }
    // zero padded tW2 rows o'=10..15 (offsets 320..511, disjoint from above)
    if (seg == 0 && t < 192) tW2bf[m * 512 + 320 + t] = __float2bfloat16(0.f);
}

// =====================================================================
// Kernel 2: main loop.  256 blocks (1/CU) x 1024 thr (16 waves, 4/SIMD).
// Block: 8 tiles of 8 data rows; rows staged f32->bf16 in LDS,
// double-buffered; each wave stages a HALF row (8KB); waves split the
// 100 m's (6-7 each); 3x mfma_16x16x32_bf16 per (tile, m); outT
// accumulated in C-frag across m; cross-wave reduce per tile.
// =====================================================================
__global__ __launch_bounds__(1024) void main_kernel(
    const float* __restrict__ data,
    const char* __restrict__ ws,
    float* __restrict__ out)
{
    extern __shared__ char smem[];
    const int tid  = threadIdx.x;
    const int lane = tid & 63;
    const int wave = tid >> 6;       // 0..15
    const int kg   = lane >> 4;      // 0..3  (MFMA k-group)
    const int ln15 = lane & 15;
    const int srow  = wave >> 1;     // staging: row 0..7
    const int shalf = wave & 1;      // staging: half 0/1

    float* tb2s = (float*)(smem + TB2OFF);
    if (tid < OUT_W) {               // b-independent bias term: sum_m tb2[m][o]
        const float* tb2f = (const float*)(ws + WS_TB2);
        float s = 0.f;
        for (int m = 0; m < M_N; ++m) s += tb2f[m * 16 + tid];
        tb2s[tid] = s;
    }

    const int tile0 = blockIdx.x * 8;
    const int mlo = (wave * M_N) >> 4;
    const int mhi = ((wave + 1) * M_N) >> 4;

    float4 v[8];                     // staging registers (half row / wave)

    // ---- prologue: stage tile0 into buf0 ----
    {
        const float* rp = data + (size_t)(tile0 * 8 + srow) * INP_N + shalf * 2048;
        #pragma unroll
        for (int j = 0; j < 4; ++j) {
            v[2 * j]     = *(const float4*)(rp + j * 512 + lane * 8);
            v[2 * j + 1] = *(const float4*)(rp + j * 512 + lane * 8 + 4);
        }
        char* bp = smem + srow * ROWB + shalf * 4096;
        #pragma unroll
        for (int j = 0; j < 4; ++j) {
            uint4 pk;
            pk.x = pkbf(v[2 * j].x,     v[2 * j].y);
            pk.y = pkbf(v[2 * j].z,     v[2 * j].w);
            pk.z = pkbf(v[2 * j + 1].x, v[2 * j + 1].y);
            pk.w = pkbf(v[2 * j + 1].z, v[2 * j + 1].w);
            *(uint4*)(bp + j * 1024 + lane * 16) = pk;
        }
    }
    __syncthreads();

    for (int ti = 0; ti < 8; ++ti) {
        const int cur = ti & 1;
        // issue next-tile global loads EARLY (hide HBM under compute)
        if (ti < 7) {
            const float* rp = data + (size_t)((tile0 + ti + 1) * 8 + srow) * INP_N + shalf * 2048;
            #pragma unroll
            for (int j = 0; j < 4; ++j) {
                v[2 * j]     = *(const float4*)(rp + j * 512 + lane * 8);
                v[2 * j + 1] = *(const float4*)(rp + j * 512 + lane * 8 + 4);
            }
        }

        // ---- compute current tile ----
        const char* gbase = smem + cur * BUFB + (lane & 7) * ROWB;
        float* thp = (float*)(smem + THOFF + wave * THWB);
        f32x4 acc = {0.f, 0.f, 0.f, 0.f};

        for (int m = mlo; m < mhi; ++m) {
            // A-frag: md[b=ln15][k=kg*8+j] gathered from staged bf16 row
            const uint4 cw = *(const uint4*)(ws + WS_COL + m * 64 + kg * 16);
            unsigned short u0 = *(const unsigned short*)(gbase + 2 * (cw.x & 0xFFFFu));
            unsigned short u1 = *(const unsigned short*)(gbase + 2 * (cw.x >> 16));
            unsigned short u2 = *(const unsigned short*)(gbase + 2 * (cw.y & 0xFFFFu));
            unsigned short u3 = *(const unsigned short*)(gbase + 2 * (cw.y >> 16));
            unsigned short u4 = *(const unsigned short*)(gbase + 2 * (cw.z & 0xFFFFu));
            unsigned short u5 = *(const unsigned short*)(gbase + 2 * (cw.z >> 16));
            unsigned short u6 = *(const unsigned short*)(gbase + 2 * (cw.w & 0xFFFFu));
            unsigned short u7 = *(const unsigned short*)(gbase + 2 * (cw.w >> 16));
            union { unsigned int ui[4]; bf16x8 v8; } af;
            af.ui[0] = (unsigned int)u0 | ((unsigned int)u1 << 16);
            af.ui[1] = (unsigned int)u2 | ((unsigned int)u3 << 16);
            af.ui[2] = (unsigned int)u4 | ((unsigned int)u5 << 16);
            af.ui[3] = (unsigned int)u6 | ((unsigned int)u7 << 16);

            // B-frags: tW1[m][h][k] rows (h=ln15 and h=ln15+16), 8 consecutive k
            const bf16x8 w1a = *(const bf16x8*)(ws + WS_TW1 + m * 2048 + ln15 * 64 + kg * 16);
            const bf16x8 w1b = *(const bf16x8*)(ws + WS_TW1 + m * 2048 + 1024 + ln15 * 64 + kg * 16);
            const bf16x8 w2f = *(const bf16x8*)(ws + WS_TW2 + m * 1024 + ln15 * 64 + kg * 16);
            const float tb10 = *(const float*)(ws + WS_TB1 + m * 128 + ln15 * 4);
            const float tb11 = *(const float*)(ws + WS_TB1 + m * 128 + 64 + ln15 * 4);

            f32x4 c0 = {tb10, tb10, tb10, tb10};   // bias as C-in (free add)
            f32x4 c1 = {tb11, tb11, tb11, tb11};
            c0 = __builtin_amdgcn_mfma_f32_16x16x32_bf16(af.v8, w1a, c0, 0, 0, 0);
            c1 = __builtin_amdgcn_mfma_f32_16x16x32_bf16(af.v8, w1b, c1, 0, 0, 0);

            // relu + bounce th (rows b=0..7 only; C row=(lane>>4)*4+r, col h=ln15)
            if (lane < 32) {
                const int b0 = kg * 4;
                #pragma unroll
                for (int r = 0; r < 4; ++r) {
                    thp[(b0 + r) * 36 + ln15]      = fmaxf(c0[r], 0.f);
                    thp[(b0 + r) * 36 + ln15 + 16] = fmaxf(c1[r], 0.f);
                }
            }
            // stage2 B-frag: th[b=ln15(&7)][h=kg*8+j] -> bf16
            const float4 t0 = *(const float4*)(thp + (lane & 7) * 36 + kg * 8);
            const float4 t1 = *(const float4*)(thp + (lane & 7) * 36 + kg * 8 + 4);
            union { unsigned int ui[4]; bf16x8 v8; } bfr;
            bfr.ui[0] = pkbf(t0.x, t0.y);
            bfr.ui[1] = pkbf(t0.z, t0.w);
            bfr.ui[2] = pkbf(t1.x, t1.y);
            bfr.ui[3] = pkbf(t1.z, t1.w);
            // outT[o][b] += tW2[o][h] x th[h][b]
            acc = __builtin_amdgcn_mfma_f32_16x16x32_bf16(w2f, bfr.v8, acc, 0, 0, 0);
        }

        // per-wave partial outT -> red (aliases own th region; safe)
        {
            float* red = (float*)(smem + THOFF + wave * THWB);
            #pragma unroll
            for (int r = 0; r < 4; ++r)
                red[(kg * 4 + r) * 16 + ln15] = acc[r];
        }
        // cvt + write next tile into the other buffer
        if (ti < 7) {
            char* bp = smem + (1 - cur) * BUFB + srow * ROWB + shalf * 4096;
            #pragma unroll
            for (int j = 0; j < 4; ++j) {
                uint4 pk;
                pk.x = pkbf(v[2 * j].x,     v[2 * j].y);
                pk.y = pkbf(v[2 * j].z,     v[2 * j].w);
                pk.z = pkbf(v[2 * j + 1].x, v[2 * j + 1].y);
                pk.w = pkbf(v[2 * j + 1].z, v[2 * j + 1].w);
                *(uint4*)(bp + j * 1024 + lane * 16) = pk;
            }
        }
        __syncthreads();

        // reduce 16 waves + tb2 + mean, write out
        if (tid < 80) {
            const int o = tid >> 3, b = tid & 7;
            float s = tb2s[o];
            #pragma unroll
            for (int w = 0; w < NWAVE; ++w)
                s += ((const float*)(smem + THOFF + w * THWB))[o * 16 + b];
            out[(size_t)((tile0 + ti) * 8 + b) * OUT_W + o] = s * 0.01f;
        }
        __syncthreads();   // protect red/th alias + buffers before next tile
    }
}

extern "C" void kernel_launch(void* const* d_in, const int* in_sizes, int n_in,
                              void* d_out, int out_size, void* d_ws, size_t ws_size,
                              hipStream_t stream) {
    const float* data = (const float*)d_in[0];
    const int*   idx  = (const int*)d_in[1];
    const float* Wi = (const float*)d_in[2];
    const float* bi = (const float*)d_in[3];
    const float* W1 = (const float*)d_in[4];
    const float* b1 = (const float*)d_in[5];
    const float* W2 = (const float*)d_in[6];
    const float* b2 = (const float*)d_in[7];
    const float* Wo = (const float*)d_in[8];
    const float* bo = (const float*)d_in[9];
    float* out = (float*)d_out;
    char* ws = (char*)d_ws;

    (void)hipFuncSetAttribute((const void*)main_kernel,
                              hipFuncAttributeMaxDynamicSharedMemorySize, LDS_SZ);

    hipLaunchKernelGGL(hyperA_kernel, dim3(M_N), dim3(256), 0, stream,
                       idx, Wi, bi, W1, b1, W2, b2, ws);
    hipLaunchKernelGGL(hyperB_kernel, dim3(M_N, 6), dim3(256), 0, stream,
                       Wo, bo, ws);
    hipLaunchKernelGGL(main_kernel, dim3(256), dim3(1024), LDS_SZ, stream,
                       data, ws, out);
}